// Round 13
// baseline (173.623 us; speedup 1.0000x reference)
//
#include <hip/hip_runtime.h>

// 3x3 conv (sparse weights treated dense), NCHW/OIHW, stride1 pad1, fp32 I/O.
// B=32, CIN=COUT=256, H=W=56.
//
// R13 = R12 + rolling single-X buffer (LDS 64->48KB -> 3 blocks/CU).
//  Taps 0-2 read X rows 0-1, taps 3-5 rows 1-2, taps 6-8 rows 2-3 -> row r's
//  last reader is tap {2,5,8}. Stage row0(cb+1) at tap2-tail, row1 at tap5,
//  rows2+3 at tap8 into the SAME buffer (after the post-MFMA barrier).
//  X layout: 4 row-regions of 256 chunks (64B slots: chunk = row*256+col*4+g),
//  64-aligned so swz(c)=c^((c>>3)&7) stays in-region (both-sides, proven R12).
//  vmcnt per tap (FIFO-derived, never 0 mid-loop): {6,6,4,5,5,4,5,5,4}.
//  Dummy A/X stages at cb=7 / t>=70 keep counts uniform (dead targets).
//  A path, m4n7 wave shape, 2 barriers/tap: unchanged from R12.

typedef __attribute__((ext_vector_type(8))) short short8;
typedef __attribute__((ext_vector_type(4))) float f32x4;
typedef __attribute__((ext_vector_type(4))) int i32x4;

constexpr int BB = 32, CIN = 256, COUT = 256, H = 56, W = 56, HW = H * W;
constexpr int HP = 58, WP = 58;

constexpr size_t XP_ELEMS = (size_t)BB * HP * WP * CIN;
constexpr size_t WB_ELEMS = (size_t)COUT * 9 * CIN;
constexpr size_t WS_NEEDED = (XP_ELEMS + WB_ELEMS) * 2;

__device__ __forceinline__ ushort f2bf(float f) {
    unsigned x = __float_as_uint(f);
    unsigned r = (x + 0x7FFFu + ((x >> 16) & 1u)) >> 16;   // RNE
    return (ushort)r;
}

// ---------------- prep kernels (unchanged) ----------------

__global__ __launch_bounds__(256)
void prep_xp(const float* __restrict__ x, ushort* __restrict__ xp) {
    const int bi = blockIdx.x;            // b*58 + padded row i
    const int b = bi / HP, i = bi % HP;
    ushort* dst = xp + (size_t)bi * WP * CIN;
    const int tid = threadIdx.x;

    if (i == 0 || i == HP - 1) {
        i32x4 z = {0, 0, 0, 0};
        for (int k = tid; k < WP * CIN / 8; k += 256) ((i32x4*)dst)[k] = z;
        return;
    }

    __shared__ ushort t[W][CIN + 2];
    const int lane = tid & 63, wv = tid >> 6;
    if (lane < W) {
        const float* src = x + (size_t)b * CIN * HW + (size_t)(i - 1) * W + lane;
        for (int cin = wv; cin < CIN; cin += 4)
            t[lane][cin] = f2bf(src[(size_t)cin * HW]);
    }
    __syncthreads();
    for (int c = 0; c < WP; ++c)
        dst[c * CIN + tid] = (c == 0 || c == WP - 1) ? (ushort)0 : t[c - 1][tid];
}

// wb2: [t = cb*9+tap][cout][ci], ci = cin%32. Slab = 8192 elems.
__global__ __launch_bounds__(256)
void prep_wb2(const float* __restrict__ w, ushort* __restrict__ wb2) {
    const int d = blockIdx.x * 256 + threadIdx.x;
    const int ci = d & 31;
    const int cout = (d >> 5) & 255;
    const int r = d >> 13;                // 0..71
    const int tap = r % 9, cb = r / 9;
    const int cin = cb * 32 + ci;
    wb2[d] = f2bf(w[((size_t)cout * CIN + cin) * 9 + tap]);
}

// ---------------- MFMA conv ----------------

#define SCHED_FENCE() __builtin_amdgcn_sched_barrier(0)
#define WAITV0 asm volatile("s_waitcnt vmcnt(0)" ::: "memory")
#define WAITV4 asm volatile("s_waitcnt vmcnt(4)" ::: "memory")
#define WAITV5 asm volatile("s_waitcnt vmcnt(5)" ::: "memory")
#define WAITV6 asm volatile("s_waitcnt vmcnt(6)" ::: "memory")

__device__ __forceinline__ void gload_lds16(const ushort* g, ushort* l) {
    __builtin_amdgcn_global_load_lds(
        (const __attribute__((address_space(1))) void*)g,
        (__attribute__((address_space(3))) void*)l, 16, 0, 0);
}

// 16B-chunk involution: mixes bits 3-5 into 0-2; self-inverse; bits>=6 fixed.
__device__ __forceinline__ int swz(int c) { return c ^ ((c >> 3) & 7); }

__global__ __launch_bounds__(256, 2)
void conv_mfma(const ushort* __restrict__ xp, const ushort* __restrict__ wb2,
               float* __restrict__ out) {
    // XCD-aware swizzle: 896 blocks = 8 * 112
    int bx = blockIdx.x;
    bx = (bx & 7) * 112 + (bx >> 3);

    const int b  = bx / 28;
    const int p0 = (bx % 28) * 112;        // 112-pix strip = 2 output rows
    const int r0 = p0 / 56;                // first padded input row

    const int tid  = threadIdx.x;
    const int wv   = tid >> 6;             // 0..3, wave -> couts [64wv, 64wv+64)
    const int lane = tid & 63;
    const int ml   = lane & 15;
    const int g    = lane >> 4;

    __shared__ ushort As0[8192], As1[8192];  // 2 x 16KB A (parity = t&1)
    __shared__ ushort Xs[8192];              // 16KB X: 4 row-regions x 256 chunks

    // A-frag read byte offsets (swizzled, constant per thread)
    int aoffB[4];
    #pragma unroll
    for (int mi = 0; mi < 4; ++mi)
        aoffB[mi] = swz((64 * wv + 16 * mi + ml) * 4 + g) * 16;
    // B-frag chunk bases: pixel p_ = p0+16nf+ml -> hl*256 + col*4 + g
    int cbase[7];
    #pragma unroll
    for (int nf = 0; nf < 7; ++nf) {
        const int p_  = p0 + 16 * nf + ml;
        const int hl  = (p_ >= p0 + 56) ? 1 : 0;
        const int col = p_ - 56 * (r0 + hl);
        cbase[nf] = hl * 256 + col * 4 + g;
    }
    // A staging source offsets: position q = k*256+tid holds chunk swz(q)
    int goffA[4];
    #pragma unroll
    for (int k = 0; k < 4; ++k) {
        const int c = swz(k * 256 + tid);
        goffA[k] = (c >> 2) * 32 + (c & 3) * 8;                 // slab elems
    }
    // X row staging: position (rr*256 + tid) holds chunk rr*256 + ii,
    // ii = (tid & 0xC0) | swz6(tid & 63); real iff ii < 232.
    int xoff;
    {
        const int ii = (tid & 0xC0) | ((tid & 63) ^ (((tid & 63) >> 3) & 7));
        xoff = (ii < 232) ? ((ii >> 2) * CIN + (ii & 3) * 8) : 0;
    }
    const size_t xbase = ((size_t)b * HP + r0) * WP * CIN;

    f32x4 acc[4][7] = {};

    #define STAGE_A(SLAB, BUF)                                                  \
        { const ushort* _s = wb2 + (size_t)(SLAB) * 8192;                       \
          _Pragma("unroll")                                                     \
          for (int k = 0; k < 4; ++k)                                           \
              gload_lds16(_s + goffA[k], &(BUF)[(k * 256 + wv * 64) * 8]); }
    // one gload per thread: row RR of cin-block CBN -> Xs row region RR
    #define STAGE_XROW(RR, CBN)                                                 \
        gload_lds16(xp + xbase + (size_t)(RR) * WP * CIN + (CBN) * 32 + xoff,   \
                    &Xs[((RR) * 256 + wv * 64) * 8])

    // prologue: X rows 0-3 of cb0, A(0)->As0, A(1)->As1; full drain; sync
    STAGE_XROW(0, 0); STAGE_XROW(1, 0); STAGE_XROW(2, 0); STAGE_XROW(3, 0);
    STAGE_A(0, As0);
    STAGE_A(1, As1);
    WAITV0;
    __syncthreads();

    for (int cb = 0; cb < 8; ++cb) {
        const int par = cb & 1;
        const int cbn = (cb < 7) ? cb + 1 : 0;   // dummy re-stage at cb7 (dead rows)
        #pragma unroll
        for (int tap = 0; tap < 9; ++tap) {
            // head: retire A(t) (+X rows staged earlier), FIFO-derived counts
            if      (tap == 0 || tap == 1) { WAITV6; }
            else if (tap == 2 || tap == 5 || tap == 8) { WAITV4; }
            else                            { WAITV5; }
            SCHED_FENCE();
            __builtin_amdgcn_s_barrier();
            SCHED_FENCE();

            // compute
            const ushort* Ab = (par ^ (tap & 1)) ? As1 : As0;
            const int kh = tap / 3, kw = tap - kh * 3;

            short8 av[4], bv[7];
            #pragma unroll
            for (int mi = 0; mi < 4; ++mi)
                av[mi] = *(const short8*)((const char*)Ab + aoffB[mi]);
            #pragma unroll
            for (int nf = 0; nf < 7; ++nf) {
                const int c = cbase[nf] + kh * 256 + kw * 4;
                bv[nf] = *(const short8*)((const char*)Xs + swz(c) * 16);
            }

            __builtin_amdgcn_s_setprio(1);
            #pragma unroll
            for (int mi = 0; mi < 4; ++mi)
                #pragma unroll
                for (int nf = 0; nf < 7; ++nf)
                    acc[mi][nf] = __builtin_amdgcn_mfma_f32_16x16x32_bf16(
                                      av[mi], bv[nf], acc[mi][nf], 0, 0, 0);
            __builtin_amdgcn_s_setprio(0);
            SCHED_FENCE();
            __builtin_amdgcn_s_barrier();    // all waves done reading
            SCHED_FENCE();

            // tail: stage A(t+2) into the parity buffer just read; X rows roll
            {
                int t2 = cb * 9 + tap + 2;
                if (t2 >= 72) t2 -= 72;      // dummy (dead target, drained at end)
                ushort* abuf = (par ^ (tap & 1)) ? As1 : As0;
                STAGE_A(t2, abuf);
            }
            if (tap == 2) { STAGE_XROW(0, cbn); }
            else if (tap == 5) { STAGE_XROW(1, cbn); }
            else if (tap == 8) { STAGE_XROW(2, cbn); STAGE_XROW(3, cbn); }
            SCHED_FENCE();
        }
    }
    WAITV0;                                  // drain tail dummy stages

    // epilogue: D[row=4g+r][col=ml] (verified R2-R12)
    float* ob = out + (size_t)b * COUT * HW;
    #pragma unroll
    for (int mi = 0; mi < 4; ++mi)
        #pragma unroll
        for (int nf = 0; nf < 7; ++nf)
            #pragma unroll
            for (int r = 0; r < 4; ++r) {
                const int cout_l = 64 * wv + 16 * mi + 4 * g + r;
                const int p_ = p0 + 16 * nf + ml;
                ob[(size_t)cout_l * HW + p_] = acc[mi][nf][r];
            }
    #undef STAGE_A
    #undef STAGE_XROW
}

// ---------------- R1 fallback (fp32 sparse direct) ----------------

constexpr int WSZ = CIN * 9;
constexpr int NIN = 54 * 54;

__global__ __launch_bounds__(256)
void sparse_conv3x3(const float* __restrict__ x,
                    const float* __restrict__ wgt,
                    float* __restrict__ out) {
    const int bc = blockIdx.x, cout = bc % COUT, b = bc / COUT;
    const int tid = threadIdx.x;
    __shared__ int2 s_ent[WSZ];
    __shared__ unsigned char s_kk[WSZ];
    __shared__ int s_cnt[257];
    const float* wc = wgt + (size_t)cout * WSZ;
    float mv[9]; int cnt = 0;
    #pragma unroll
    for (int i = 0; i < 9; ++i) { mv[i] = wc[tid * 9 + i]; if (mv[i] != 0.0f) cnt++; }
    s_cnt[tid] = cnt; __syncthreads();
    if (tid == 0) { int run = 0; for (int t = 0; t < 256; ++t) { int c = s_cnt[t]; s_cnt[t] = run; run += c; } s_cnt[256] = run; }
    __syncthreads();
    { int pos = s_cnt[tid];
      #pragma unroll
      for (int i = 0; i < 9; ++i) if (mv[i] != 0.0f) {
          const int kh = i / 3, kw = i - kh * 3;
          int2 e; e.x = (tid * HW + (kh - 1) * W + (kw - 1)) * 4; e.y = __float_as_int(mv[i]);
          s_ent[pos] = e; s_kk[pos] = (unsigned char)(kh | (kw << 4)); pos++; } }
    __syncthreads();
    const int nnz = s_cnt[256];
    const char* xb = (const char*)(x + (size_t)b * CIN * HW);
    float* ob = out + (size_t)bc * HW;
    for (int o = tid; o < HW; o += 256) {
        int h, w; bool interior = (o < NIN);
        if (interior) { h = 1 + o / 54; w = 1 + (o - (h - 1) * 54); }
        else { int o2 = o - NIN;
            if (o2 < 56) { h = 0; w = o2; } else if (o2 < 112) { h = 55; w = o2 - 56; }
            else if (o2 < 166) { h = 1 + (o2 - 112); w = 0; } else { h = 1 + (o2 - 166); w = 55; } }
        const char* pb = xb + (size_t)(h * W + w) * 4;
        float acc = 0.0f;
        if (interior) {
            #pragma unroll 4
            for (int e = 0; e < nnz; ++e) { const int2 en = s_ent[e];
                acc = fmaf(__int_as_float(en.y), *(const float*)(pb + en.x), acc); }
        } else {
            const int h1 = h - 1, w1 = w - 1;
            for (int e = 0; e < nnz; ++e) { const int2 en = s_ent[e]; const int kk = s_kk[e];
                const int hh = h1 + (kk & 15), ww = w1 + (kk >> 4);
                if ((unsigned)hh < (unsigned)H && (unsigned)ww < (unsigned)W)
                    acc = fmaf(__int_as_float(en.y), *(const float*)(pb + en.x), acc); } }
        ob[h * W + w] = acc;
    }
}

// ---------------- launch ----------------

extern "C" void kernel_launch(void* const* d_in, const int* in_sizes, int n_in,
                              void* d_out, int out_size, void* d_ws, size_t ws_size,
                              hipStream_t stream) {
    const float* x = (const float*)d_in[0];
    const float* w = (const float*)d_in[1];
    float* out = (float*)d_out;

    if (ws_size >= WS_NEEDED) {
        ushort* xp = (ushort*)d_ws;
        ushort* wbp = xp + XP_ELEMS;
        prep_xp<<<BB * HP, 256, 0, stream>>>(x, xp);
        prep_wb2<<<(int)(WB_ELEMS / 256), 256, 0, stream>>>(w, wbp);
        conv_mfma<<<896, 256, 0, stream>>>(xp, wbp, out);
    } else {
        sparse_conv3x3<<<BB * COUT, 256, 0, stream>>>(x, w, out);
    }
}